// Round 1
// baseline (339.017 us; speedup 1.0000x reference)
//
#include <hip/hip_runtime.h>
#include <hip/hip_bf16.h>

namespace {

constexpr int B_   = 4;
constexpr int CIN  = 64;
constexpr int COUT = 128;
constexpr int HIN  = 64,  WIN  = 1024;
constexpr int HOUT = 32,  WOUT = 512;
constexpr int TW   = 16;        // wo positions per block
constexpr int SP   = 1096;      // per-position S stride in bf16 elems (2192 B: mult16, !=0 mod 128)
constexpr int KTOT = CIN * 16;  // 1024

typedef __bf16 bf16x8 __attribute__((ext_vector_type(8)));
typedef float  f32x4  __attribute__((ext_vector_type(4)));

// wcb[o][tap*64+c] = Wc[o][c*16+tap] (bf16);  w2t[c][c1] = W2[c1][c] (bf16)
__global__ void cvt_wts(const float* __restrict__ Wc, const float* __restrict__ W2,
                        __hip_bfloat16* __restrict__ wcb, __hip_bfloat16* __restrict__ w2t) {
    int i = blockIdx.x * 256 + threadIdx.x;
    if (i < COUT * KTOT) {
        int o = i >> 10, k = i & 1023, tap = k >> 6, c = k & 63;
        wcb[i] = __float2bfloat16(Wc[(size_t)o * KTOT + c * 16 + tap]);
    } else if (i < COUT * KTOT + CIN * CIN) {
        int m = i - COUT * KTOT;
        int c = m >> 6, c1 = m & 63;
        w2t[m] = __float2bfloat16(W2[c1 * CIN + c]);
    }
}

__global__ __launch_bounds__(256, 4)
void fused_ccconv(const float* __restrict__ x,  const float* __restrict__ r,
                  const float* __restrict__ W1, const float* __restrict__ b1,
                  const __hip_bfloat16* __restrict__ W2T, const float* __restrict__ b2,
                  const __hip_bfloat16* __restrict__ WcB, const float* __restrict__ bc,
                  float* __restrict__ out)
{
    // Per position p: elems [0,1088) hold w[tap][c] (stride 68, b64-aligned) during phase 1,
    // then A[k'=tap*64+c] overwrites [0,1024) in phase 1c (same wave owns both -> in-order DS).
    // A's 16B chunks are XOR-swizzled within each 128B tap-row to kill ds_write bank conflicts.
    __shared__ __hip_bfloat16 S[TW * SP];   // 35,072 B

    const int t   = threadIdx.x;
    const int bx  = blockIdx.x;
    const int wt  = bx & 31;
    const int ho  = (bx >> 5) & 31;
    const int b   = bx >> 10;
    const int wo0 = wt * TW;

    const float* rb = r + (size_t)b * HIN * WIN;

    // ---- phase-1c identity, computed up-front so x loads can be hoisted ----
    const int pp    = t >> 4;         // position within tile
    const int ptap  = t & 15;         // tap
    const int pi    = ptap >> 2, pj = ptap & 3;
    const int phsrc = (2*ho + pj + 63) & 63;
    const int pwsrc = 2*(wo0 + pp) + pi - 1;
    const bool pinb = (unsigned)pwsrc < (unsigned)WIN;
    const float* xb = x + (size_t)b*CIN*HIN*WIN + phsrc*WIN + pwsrc;

    // Hoisted x loads (c = 0..31): independent of everything, latency hides
    // under phase 1b's VALU block instead of stalling phase 1c.
    float xlo[32];
    #pragma unroll
    for (int c = 0; c < 32; ++c)
        xlo[c] = pinb ? xb[(size_t)c * HIN * WIN] : 0.0f;

    // ---- output 1: r_center ----
    if (t < TW) {
        const int wo = wo0 + t;
        out[(size_t)B_*COUT*HOUT*WOUT + ((size_t)b*HOUT + ho)*WOUT + wo] =
            rb[(2*ho + 1)*WIN + (2*wo + 1)];
    }

    const int ln   = t & 63;
    const int wv   = t >> 6;
    const int lm   = ln & 15;
    const int quad = ln >> 4;

    const float AZI = 0.006135923151542565f;  // 2*pi/1024
    const float INC = 0.0073f;

    // ================= phase 1b: w = leaky(pe@W1+b1)@W2 + b2 via MFMA =================
    {
        // B-frags (W2T) from global, L1-hot: lane holds W2T[nt*16+lm][k..k+7]
        bf16x8 bfr[4][2];
        float  b2v[4];
        #pragma unroll
        for (int nt = 0; nt < 4; ++nt) {
            #pragma unroll
            for (int ks = 0; ks < 2; ++ks)
                bfr[nt][ks] = *reinterpret_cast<const bf16x8*>(
                    W2T + (nt*16 + lm)*CIN + ks*32 + quad*8);
            b2v[nt] = b2[nt*16 + lm];
        }

        // this lane's tap (A-operand row) = lm
        const int i_ = lm >> 2, j_ = lm & 3;
        const float di = (float)(i_ - 2), dj = (float)(j_ - 2);
        const float cA = cosf(AZI * dj), sA = sinf(AZI * dj);
        const float cI = cosf(INC * di), sI = sinf(INC * di);
        const int hsrc = (2*ho + j_ + 63) & 63;

        #pragma unroll
        for (int mt = 0; mt < 4; ++mt) {
            const int p  = wv*4 + mt;
            const int wo = wo0 + p;
            const int wsrc = 2*wo + i_ - 1;
            const bool inb = (unsigned)wsrc < (unsigned)WIN;
            const float rpv = inb ? rb[hsrc*WIN + wsrc] : 100.0f;
            const float rc  = rb[(2*ho + 1)*WIN + (2*wo + 1)];
            const float pe0 = rpv * cA * cI - rc;
            const float pe1 = rpv * cA * sI;
            const float pe2 = rpv * sA;

            // A-frags: lane holds h[tap=lm][c1 = ks*32 + quad*8 + j]
            bf16x8 af0, af1;
            #pragma unroll
            for (int ks = 0; ks < 2; ++ks) {
                const int cb = ks*32 + quad*8;
                #pragma unroll
                for (int j = 0; j < 8; ++j) {
                    const int c1 = cb + j;
                    float hv = fmaf(pe0, W1[c1],
                               fmaf(pe1, W1[CIN + c1],
                               fmaf(pe2, W1[2*CIN + c1], b1[c1])));
                    hv = (hv >= 0.0f) ? hv : 0.2f * hv;
                    __hip_bfloat16 hb = __float2bfloat16(hv);
                    if (ks == 0) af0[j] = *reinterpret_cast<__bf16*>(&hb);
                    else         af1[j] = *reinterpret_cast<__bf16*>(&hb);
                }
            }

            #pragma unroll
            for (int nt = 0; nt < 4; ++nt) {
                f32x4 acc = {b2v[nt], b2v[nt], b2v[nt], b2v[nt]};
                acc = __builtin_amdgcn_mfma_f32_16x16x32_bf16(af0, bfr[nt][0], acc, 0, 0, 0);
                acc = __builtin_amdgcn_mfma_f32_16x16x32_bf16(af1, bfr[nt][1], acc, 0, 0, 0);
                // D: row(tap) = quad*4+q, col(c) = nt*16+lm  -> w[tap][c], stride 68
                #pragma unroll
                for (int q = 0; q < 4; ++q)
                    S[p*SP + (quad*4 + q)*68 + nt*16 + lm] = __float2bfloat16(acc[q]);
            }
        }
    }

    // ================= phase 1c: A[p][tap*64+c] = w[tap][c] * x =================
    {
        // second half of x (c = 32..63); consumed last in the g-loop below,
        // so its latency partially hides under packing of the first half.
        float xhi[32];
        #pragma unroll
        for (int c = 0; c < 32; ++c)
            xhi[c] = pinb ? xb[(size_t)(c + 32) * HIN * WIN] : 0.0f;

        // read this row's w (in-order DS => all reads precede the A-writes below)
        uint2 wrow[16];
        const uint2* wp = reinterpret_cast<const uint2*>(S + pp*SP + ptap*68);
        #pragma unroll
        for (int u = 0; u < 16; ++u) wrow[u] = wp[u];

        // XOR-swizzle of the 16B chunk within this tap's 128B row:
        // un-swizzled all 16 taps hit the same 4-bank group (16-way conflict).
        const int swz = (ptap & 7) << 4;
        char* Abase = reinterpret_cast<char*>(S + pp*SP) + ptap*128;

        #pragma unroll
        for (int g = 0; g < 8; ++g) {
            uint pk[4];
            #pragma unroll
            for (int pr = 0; pr < 4; ++pr) {
                const int c0 = g*8 + pr*2;
                const uint2 wv2 = wrow[c0 >> 2];
                const uint word = (c0 & 2) ? wv2.y : wv2.x;
                const float w0 = __uint_as_float(word << 16);
                const float w1 = __uint_as_float(word & 0xffff0000u);
                const float xv0 = (c0     < 32) ? xlo[c0]        : xhi[c0 - 32];
                const float xv1 = (c0 + 1 < 32) ? xlo[c0 + 1]    : xhi[c0 - 31];
                __hip_bfloat16 p0 = __float2bfloat16(w0 * xv0);
                __hip_bfloat16 p1 = __float2bfloat16(w1 * xv1);
                const uint lo = *reinterpret_cast<unsigned short*>(&p0);
                const uint hi = *reinterpret_cast<unsigned short*>(&p1);
                pk[pr] = lo | (hi << 16);
            }
            *reinterpret_cast<uint4*>(Abase + ((g*16) ^ swz)) =
                make_uint4(pk[0], pk[1], pk[2], pk[3]);
        }
    }

    __syncthreads();

    // ================= phase 2: out[o][p] = bc[o] + sum_k Wc[o][k']*A[p][k'] =================
    {
        const int o0 = wv * 32;
        const __hip_bfloat16* wcP0 = WcB + ((size_t)(o0 + lm)) * KTOT + quad*8;
        const __hip_bfloat16* wcP1 = wcP0 + (size_t)16 * KTOT;
        const char* aRow = reinterpret_cast<const char*>(S + lm*SP);
        const int qoff = quad << 4;

        f32x4 acc0 = {0.f,0.f,0.f,0.f};
        f32x4 acc1 = {0.f,0.f,0.f,0.f};

        #pragma unroll 8
        for (int ks = 0; ks < KTOT/32; ++ks) {
            const int tap = ks >> 1;
            const int rem = ((ks & 1) << 6) + qoff;               // byte offset within tap row
            const bf16x8 af = *reinterpret_cast<const bf16x8*>(
                aRow + tap*128 + (rem ^ ((tap & 7) << 4)));       // matches writer swizzle
            const bf16x8 w0 = *reinterpret_cast<const bf16x8*>(wcP0 + ks*32);
            const bf16x8 w1 = *reinterpret_cast<const bf16x8*>(wcP1 + ks*32);
            acc0 = __builtin_amdgcn_mfma_f32_16x16x32_bf16(w0, af, acc0, 0, 0, 0);
            acc1 = __builtin_amdgcn_mfma_f32_16x16x32_bf16(w1, af, acc1, 0, 0, 0);
        }

        #pragma unroll
        for (int q = 0; q < 4; ++q) {
            const int oa = o0 + quad*4 + q;
            const int ob = oa + 16;
            out[(((size_t)b*COUT + oa)*HOUT + ho)*WOUT + wo0 + lm] = acc0[q] + bc[oa];
            out[(((size_t)b*COUT + ob)*HOUT + ho)*WOUT + wo0 + lm] = acc1[q] + bc[ob];
        }
    }
}

} // namespace

extern "C" void kernel_launch(void* const* d_in, const int* in_sizes, int n_in,
                              void* d_out, int out_size, void* d_ws, size_t ws_size,
                              hipStream_t stream) {
    const float* x  = (const float*)d_in[0];
    const float* r  = (const float*)d_in[1];
    const float* W1 = (const float*)d_in[2];
    const float* b1 = (const float*)d_in[3];
    const float* W2 = (const float*)d_in[4];
    const float* b2 = (const float*)d_in[5];
    const float* Wc = (const float*)d_in[6];
    const float* bc = (const float*)d_in[7];
    float* out = (float*)d_out;

    __hip_bfloat16* wcb = (__hip_bfloat16*)d_ws;                       // 256 KB
    __hip_bfloat16* w2t = (__hip_bfloat16*)((char*)d_ws + 262144);     // 8 KB

    const int ntot = COUT*KTOT + CIN*CIN;   // 135168
    hipLaunchKernelGGL(cvt_wts, dim3((ntot + 255)/256), dim3(256), 0, stream,
                       Wc, W2, wcb, w2t);

    dim3 grid(B_ * HOUT * (WOUT / TW));   // 4096
    dim3 block(256);
    hipLaunchKernelGGL(fused_ccconv, grid, block, 0, stream,
                       x, r, W1, b1, w2t, b2, wcb, bc, out);
}

// Round 2
// 311.581 us; speedup vs baseline: 1.0881x; 1.0881x over previous
//
#include <hip/hip_runtime.h>
#include <hip/hip_bf16.h>

namespace {

constexpr int B_   = 4;
constexpr int CIN  = 64;
constexpr int COUT = 128;
constexpr int HIN  = 64,  WIN  = 1024;
constexpr int HOUT = 32,  WOUT = 512;
constexpr int TW   = 16;        // wo positions per block
constexpr int SP   = 1096;      // per-position S stride in bf16 elems (2192 B: mult16, !=0 mod 128)
constexpr int KTOT = CIN * 16;  // 1024

typedef __bf16 bf16x8 __attribute__((ext_vector_type(8)));
typedef float  f32x4  __attribute__((ext_vector_type(4)));

// wcb[o][tap*64+c] = Wc[o][c*16+tap] (bf16);  w2t[c][c1] = W2[c1][c] (bf16)
__global__ void cvt_wts(const float* __restrict__ Wc, const float* __restrict__ W2,
                        __hip_bfloat16* __restrict__ wcb, __hip_bfloat16* __restrict__ w2t) {
    int i = blockIdx.x * 256 + threadIdx.x;
    if (i < COUT * KTOT) {
        int o = i >> 10, k = i & 1023, tap = k >> 6, c = k & 63;
        wcb[i] = __float2bfloat16(Wc[(size_t)o * KTOT + c * 16 + tap]);
    } else if (i < COUT * KTOT + CIN * CIN) {
        int m = i - COUT * KTOT;
        int c = m >> 6, c1 = m & 63;
        w2t[m] = __float2bfloat16(W2[c1 * CIN + c]);
    }
}

// (256,3): ~170 VGPR/wave budget. (256,4) clamped to 64 VGPR and spilled the
// hoisted x arrays to scratch (+118 MB HBM traffic, r1 post-mortem). Occupancy
// is not the binding constraint (latency-bound, all pipes <15%).
__global__ __launch_bounds__(256, 3)
void fused_ccconv(const float* __restrict__ x,  const float* __restrict__ r,
                  const float* __restrict__ W1, const float* __restrict__ b1,
                  const __hip_bfloat16* __restrict__ W2T, const float* __restrict__ b2,
                  const __hip_bfloat16* __restrict__ WcB, const float* __restrict__ bc,
                  float* __restrict__ out)
{
    // Per position p: elems [0,1088) hold w[tap][c] (stride 68, b64-aligned) during phase 1,
    // then A[k'=tap*64+c] overwrites [0,1024) in phase 1c (same wave owns both -> in-order DS).
    // A's 16B chunks are XOR-swizzled within each 128B tap-row to kill ds_write bank conflicts
    // (r1: SQ_LDS_BANK_CONFLICT 9.4M -> 2.1M).
    __shared__ __hip_bfloat16 S[TW * SP];   // 35,072 B

    const int t   = threadIdx.x;
    const int bx  = blockIdx.x;
    const int wt  = bx & 31;
    const int ho  = (bx >> 5) & 31;
    const int b   = bx >> 10;
    const int wo0 = wt * TW;

    const float* rb = r + (size_t)b * HIN * WIN;

    // ---- phase-1c identity, computed up-front so x loads can be hoisted ----
    const int pp    = t >> 4;         // position within tile
    const int ptap  = t & 15;         // tap
    const int pi    = ptap >> 2, pj = ptap & 3;
    const int phsrc = (2*ho + pj + 63) & 63;
    const int pwsrc = 2*(wo0 + pp) + pi - 1;
    const bool pinb = (unsigned)pwsrc < (unsigned)WIN;
    const float* xb = x + (size_t)b*CIN*HIN*WIN + phsrc*WIN + pwsrc;

    // Hoisted x loads (c = 0..31): independent of everything, latency hides
    // under phase 1b's VALU block instead of stalling phase 1c.
    float xlo[32];
    #pragma unroll
    for (int c = 0; c < 32; ++c)
        xlo[c] = pinb ? xb[(size_t)c * HIN * WIN] : 0.0f;

    // ---- output 1: r_center ----
    if (t < TW) {
        const int wo = wo0 + t;
        out[(size_t)B_*COUT*HOUT*WOUT + ((size_t)b*HOUT + ho)*WOUT + wo] =
            rb[(2*ho + 1)*WIN + (2*wo + 1)];
    }

    const int ln   = t & 63;
    const int wv   = t >> 6;
    const int lm   = ln & 15;
    const int quad = ln >> 4;

    const float AZI = 0.006135923151542565f;  // 2*pi/1024
    const float INC = 0.0073f;

    // ================= phase 1b: w = leaky(pe@W1+b1)@W2 + b2 via MFMA =================
    {
        // B-frags (W2T) from global, L1-hot: lane holds W2T[nt*16+lm][k..k+7]
        bf16x8 bfr[4][2];
        float  b2v[4];
        #pragma unroll
        for (int nt = 0; nt < 4; ++nt) {
            #pragma unroll
            for (int ks = 0; ks < 2; ++ks)
                bfr[nt][ks] = *reinterpret_cast<const bf16x8*>(
                    W2T + (nt*16 + lm)*CIN + ks*32 + quad*8);
            b2v[nt] = b2[nt*16 + lm];
        }

        // this lane's tap (A-operand row) = lm
        const int i_ = lm >> 2, j_ = lm & 3;
        const float di = (float)(i_ - 2), dj = (float)(j_ - 2);
        const float cA = cosf(AZI * dj), sA = sinf(AZI * dj);
        const float cI = cosf(INC * di), sI = sinf(INC * di);
        const int hsrc = (2*ho + j_ + 63) & 63;

        #pragma unroll
        for (int mt = 0; mt < 4; ++mt) {
            const int p  = wv*4 + mt;
            const int wo = wo0 + p;
            const int wsrc = 2*wo + i_ - 1;
            const bool inb = (unsigned)wsrc < (unsigned)WIN;
            const float rpv = inb ? rb[hsrc*WIN + wsrc] : 100.0f;
            const float rc  = rb[(2*ho + 1)*WIN + (2*wo + 1)];
            const float pe0 = rpv * cA * cI - rc;
            const float pe1 = rpv * cA * sI;
            const float pe2 = rpv * sA;

            // A-frags: lane holds h[tap=lm][c1 = ks*32 + quad*8 + j]
            bf16x8 af0, af1;
            #pragma unroll
            for (int ks = 0; ks < 2; ++ks) {
                const int cb = ks*32 + quad*8;
                #pragma unroll
                for (int j = 0; j < 8; ++j) {
                    const int c1 = cb + j;
                    float hv = fmaf(pe0, W1[c1],
                               fmaf(pe1, W1[CIN + c1],
                               fmaf(pe2, W1[2*CIN + c1], b1[c1])));
                    hv = (hv >= 0.0f) ? hv : 0.2f * hv;
                    __hip_bfloat16 hb = __float2bfloat16(hv);
                    if (ks == 0) af0[j] = *reinterpret_cast<__bf16*>(&hb);
                    else         af1[j] = *reinterpret_cast<__bf16*>(&hb);
                }
            }

            #pragma unroll
            for (int nt = 0; nt < 4; ++nt) {
                f32x4 acc = {b2v[nt], b2v[nt], b2v[nt], b2v[nt]};
                acc = __builtin_amdgcn_mfma_f32_16x16x32_bf16(af0, bfr[nt][0], acc, 0, 0, 0);
                acc = __builtin_amdgcn_mfma_f32_16x16x32_bf16(af1, bfr[nt][1], acc, 0, 0, 0);
                // D: row(tap) = quad*4+q, col(c) = nt*16+lm  -> w[tap][c], stride 68
                #pragma unroll
                for (int q = 0; q < 4; ++q)
                    S[p*SP + (quad*4 + q)*68 + nt*16 + lm] = __float2bfloat16(acc[q]);
            }
        }
    }

    // ================= phase 1c: A[p][tap*64+c] = w[tap][c] * x =================
    {
        // second half of x (c = 32..63); consumed last in the g-loop below,
        // so its latency partially hides under packing of the first half.
        float xhi[32];
        #pragma unroll
        for (int c = 0; c < 32; ++c)
            xhi[c] = pinb ? xb[(size_t)(c + 32) * HIN * WIN] : 0.0f;

        // read this row's w (in-order DS => all reads precede the A-writes below)
        uint2 wrow[16];
        const uint2* wp = reinterpret_cast<const uint2*>(S + pp*SP + ptap*68);
        #pragma unroll
        for (int u = 0; u < 16; ++u) wrow[u] = wp[u];

        // XOR-swizzle of the 16B chunk within this tap's 128B row:
        // un-swizzled all 16 taps hit the same 4-bank group (16-way conflict).
        const int swz = (ptap & 7) << 4;
        char* Abase = reinterpret_cast<char*>(S + pp*SP) + ptap*128;

        #pragma unroll
        for (int g = 0; g < 8; ++g) {
            uint pk[4];
            #pragma unroll
            for (int pr = 0; pr < 4; ++pr) {
                const int c0 = g*8 + pr*2;
                const uint2 wv2 = wrow[c0 >> 2];
                const uint word = (c0 & 2) ? wv2.y : wv2.x;
                const float w0 = __uint_as_float(word << 16);
                const float w1 = __uint_as_float(word & 0xffff0000u);
                const float xv0 = (c0     < 32) ? xlo[c0]        : xhi[c0 - 32];
                const float xv1 = (c0 + 1 < 32) ? xlo[c0 + 1]    : xhi[c0 - 31];
                __hip_bfloat16 p0 = __float2bfloat16(w0 * xv0);
                __hip_bfloat16 p1 = __float2bfloat16(w1 * xv1);
                const uint lo = *reinterpret_cast<unsigned short*>(&p0);
                const uint hi = *reinterpret_cast<unsigned short*>(&p1);
                pk[pr] = lo | (hi << 16);
            }
            *reinterpret_cast<uint4*>(Abase + ((g*16) ^ swz)) =
                make_uint4(pk[0], pk[1], pk[2], pk[3]);
        }
    }

    __syncthreads();

    // ================= phase 2: out[o][p] = bc[o] + sum_k Wc[o][k']*A[p][k'] =================
    {
        const int o0 = wv * 32;
        const __hip_bfloat16* wcP0 = WcB + ((size_t)(o0 + lm)) * KTOT + quad*8;
        const __hip_bfloat16* wcP1 = wcP0 + (size_t)16 * KTOT;
        const char* aRow = reinterpret_cast<const char*>(S + lm*SP);
        const int qoff = quad << 4;

        f32x4 acc0 = {0.f,0.f,0.f,0.f};
        f32x4 acc1 = {0.f,0.f,0.f,0.f};

        #pragma unroll 8
        for (int ks = 0; ks < KTOT/32; ++ks) {
            const int tap = ks >> 1;
            const int rem = ((ks & 1) << 6) + qoff;               // byte offset within tap row
            const bf16x8 af = *reinterpret_cast<const bf16x8*>(
                aRow + tap*128 + (rem ^ ((tap & 7) << 4)));       // matches writer swizzle
            const bf16x8 w0 = *reinterpret_cast<const bf16x8*>(wcP0 + ks*32);
            const bf16x8 w1 = *reinterpret_cast<const bf16x8*>(wcP1 + ks*32);
            acc0 = __builtin_amdgcn_mfma_f32_16x16x32_bf16(w0, af, acc0, 0, 0, 0);
            acc1 = __builtin_amdgcn_mfma_f32_16x16x32_bf16(w1, af, acc1, 0, 0, 0);
        }

        #pragma unroll
        for (int q = 0; q < 4; ++q) {
            const int oa = o0 + quad*4 + q;
            const int ob = oa + 16;
            out[(((size_t)b*COUT + oa)*HOUT + ho)*WOUT + wo0 + lm] = acc0[q] + bc[oa];
            out[(((size_t)b*COUT + ob)*HOUT + ho)*WOUT + wo0 + lm] = acc1[q] + bc[ob];
        }
    }
}

} // namespace

extern "C" void kernel_launch(void* const* d_in, const int* in_sizes, int n_in,
                              void* d_out, int out_size, void* d_ws, size_t ws_size,
                              hipStream_t stream) {
    const float* x  = (const float*)d_in[0];
    const float* r  = (const float*)d_in[1];
    const float* W1 = (const float*)d_in[2];
    const float* b1 = (const float*)d_in[3];
    const float* W2 = (const float*)d_in[4];
    const float* b2 = (const float*)d_in[5];
    const float* Wc = (const float*)d_in[6];
    const float* bc = (const float*)d_in[7];
    float* out = (float*)d_out;

    __hip_bfloat16* wcb = (__hip_bfloat16*)d_ws;                       // 256 KB
    __hip_bfloat16* w2t = (__hip_bfloat16*)((char*)d_ws + 262144);     // 8 KB

    const int ntot = COUT*KTOT + CIN*CIN;   // 135168
    hipLaunchKernelGGL(cvt_wts, dim3((ntot + 255)/256), dim3(256), 0, stream,
                       Wc, W2, wcb, w2t);

    dim3 grid(B_ * HOUT * (WOUT / TW));   // 4096
    dim3 block(256);
    hipLaunchKernelGGL(fused_ccconv, grid, block, 0, stream,
                       x, r, W1, b1, w2t, b2, wcb, bc, out);
}

// Round 3
// 292.417 us; speedup vs baseline: 1.1594x; 1.0655x over previous
//
#include <hip/hip_runtime.h>
#include <hip/hip_bf16.h>

namespace {

constexpr int B_   = 4;
constexpr int CIN  = 64;
constexpr int COUT = 128;
constexpr int HIN  = 64,  WIN  = 1024;
constexpr int HOUT = 32,  WOUT = 512;
constexpr int TW   = 16;        // wo positions per block
constexpr int SP   = 1096;      // per-position S stride in bf16 elems (2192 B: mult16, !=0 mod 128)
constexpr int KTOT = CIN * 16;  // 1024

typedef __bf16 bf16x8 __attribute__((ext_vector_type(8)));
typedef float  f32x4  __attribute__((ext_vector_type(4)));

// wcb[o][tap*64+c] = Wc[o][c*16+tap] (bf16);  w2t[c][c1] = W2[c1][c] (bf16)
__global__ void cvt_wts(const float* __restrict__ Wc, const float* __restrict__ W2,
                        __hip_bfloat16* __restrict__ wcb, __hip_bfloat16* __restrict__ w2t) {
    int i = blockIdx.x * 256 + threadIdx.x;
    if (i < COUT * KTOT) {
        int o = i >> 10, k = i & 1023, tap = k >> 6, c = k & 63;
        wcb[i] = __float2bfloat16(Wc[(size_t)o * KTOT + c * 16 + tap]);
    } else if (i < COUT * KTOT + CIN * CIN) {
        int m = i - COUT * KTOT;
        int c = m >> 6, c1 = m & 63;
        w2t[m] = __float2bfloat16(W2[c1 * CIN + c]);
    }
}

// (256,3). Do NOT hoist x loads across phase 1b: r1/r2 both showed the
// allocator spills long live-ranges to scratch regardless of VGPR budget
// (+24..66 MB HBM round-trip traffic). Short-range loads inside 1c (r0
// structure) pipeline cleanly at 68 VGPR with zero spill.
__global__ __launch_bounds__(256, 3)
void fused_ccconv(const float* __restrict__ x,  const float* __restrict__ r,
                  const float* __restrict__ W1, const float* __restrict__ b1,
                  const __hip_bfloat16* __restrict__ W2T, const float* __restrict__ b2,
                  const __hip_bfloat16* __restrict__ WcB, const float* __restrict__ bc,
                  float* __restrict__ out)
{
    // Per position p: elems [0,1088) hold w[tap][c] (stride 68, b64-aligned) during phase 1,
    // then A[k'=tap*64+c] overwrites [0,1024) in phase 1c (same wave owns both -> in-order DS).
    // A's 16B chunks are XOR-swizzled within each 128B tap-row to kill ds_write bank conflicts
    // (proven r1/r2: SQ_LDS_BANK_CONFLICT 9.4M -> 2.1M).
    __shared__ __hip_bfloat16 S[TW * SP];   // 35,072 B

    const int t   = threadIdx.x;
    const int bx  = blockIdx.x;
    const int wt  = bx & 31;
    const int ho  = (bx >> 5) & 31;
    const int b   = bx >> 10;
    const int wo0 = wt * TW;

    const float* rb = r + (size_t)b * HIN * WIN;

    // ---- output 1: r_center ----
    if (t < TW) {
        const int wo = wo0 + t;
        out[(size_t)B_*COUT*HOUT*WOUT + ((size_t)b*HOUT + ho)*WOUT + wo] =
            rb[(2*ho + 1)*WIN + (2*wo + 1)];
    }

    const int ln   = t & 63;
    const int wv   = t >> 6;
    const int lm   = ln & 15;
    const int quad = ln >> 4;

    const float AZI = 0.006135923151542565f;  // 2*pi/1024
    const float INC = 0.0073f;

    // ================= phase 1b: w = leaky(pe@W1+b1)@W2 + b2 via MFMA =================
    {
        // B-frags (W2T) from global, L1-hot: lane holds W2T[nt*16+lm][k..k+7]
        bf16x8 bfr[4][2];
        float  b2v[4];
        #pragma unroll
        for (int nt = 0; nt < 4; ++nt) {
            #pragma unroll
            for (int ks = 0; ks < 2; ++ks)
                bfr[nt][ks] = *reinterpret_cast<const bf16x8*>(
                    W2T + (nt*16 + lm)*CIN + ks*32 + quad*8);
            b2v[nt] = b2[nt*16 + lm];
        }

        // this lane's tap (A-operand row) = lm
        const int i_ = lm >> 2, j_ = lm & 3;
        const float di = (float)(i_ - 2), dj = (float)(j_ - 2);
        const float cA = cosf(AZI * dj), sA = sinf(AZI * dj);
        const float cI = cosf(INC * di), sI = sinf(INC * di);
        const int hsrc = (2*ho + j_ + 63) & 63;

        #pragma unroll
        for (int mt = 0; mt < 4; ++mt) {
            const int p  = wv*4 + mt;
            const int wo = wo0 + p;
            const int wsrc = 2*wo + i_ - 1;
            const bool inb = (unsigned)wsrc < (unsigned)WIN;
            const float rpv = inb ? rb[hsrc*WIN + wsrc] : 100.0f;
            const float rc  = rb[(2*ho + 1)*WIN + (2*wo + 1)];
            const float pe0 = rpv * cA * cI - rc;
            const float pe1 = rpv * cA * sI;
            const float pe2 = rpv * sA;

            // A-frags: lane holds h[tap=lm][c1 = ks*32 + quad*8 + j]
            bf16x8 af0, af1;
            #pragma unroll
            for (int ks = 0; ks < 2; ++ks) {
                const int cb = ks*32 + quad*8;
                #pragma unroll
                for (int j = 0; j < 8; ++j) {
                    const int c1 = cb + j;
                    float hv = fmaf(pe0, W1[c1],
                               fmaf(pe1, W1[CIN + c1],
                               fmaf(pe2, W1[2*CIN + c1], b1[c1])));
                    hv = (hv >= 0.0f) ? hv : 0.2f * hv;
                    __hip_bfloat16 hb = __float2bfloat16(hv);
                    if (ks == 0) af0[j] = *reinterpret_cast<__bf16*>(&hb);
                    else         af1[j] = *reinterpret_cast<__bf16*>(&hb);
                }
            }

            #pragma unroll
            for (int nt = 0; nt < 4; ++nt) {
                f32x4 acc = {b2v[nt], b2v[nt], b2v[nt], b2v[nt]};
                acc = __builtin_amdgcn_mfma_f32_16x16x32_bf16(af0, bfr[nt][0], acc, 0, 0, 0);
                acc = __builtin_amdgcn_mfma_f32_16x16x32_bf16(af1, bfr[nt][1], acc, 0, 0, 0);
                // D: row(tap) = quad*4+q, col(c) = nt*16+lm  -> w[tap][c], stride 68
                #pragma unroll
                for (int q = 0; q < 4; ++q)
                    S[p*SP + (quad*4 + q)*68 + nt*16 + lm] = __float2bfloat16(acc[q]);
            }
        }
    }

    // ================= phase 1c: A[p][tap*64+c] = w[tap][c] * x =================
    {
        const int p   = t >> 4;
        const int tap = t & 15;
        const int i_  = tap >> 2, j_ = tap & 3;
        const int hsrc = (2*ho + j_ + 63) & 63;
        const int wo   = wo0 + p;
        const int wsrc = 2*wo + i_ - 1;
        const bool inb = (unsigned)wsrc < (unsigned)WIN;

        // read this row's w (in-order DS => all reads precede the A-writes below)
        uint2 wrow[16];
        const uint2* wp = reinterpret_cast<const uint2*>(S + p*SP + tap*68);
        #pragma unroll
        for (int u = 0; u < 16; ++u) wrow[u] = wp[u];

        const float* xb = x + (size_t)b*CIN*HIN*WIN + hsrc*WIN + wsrc;

        // prefetch all x for deep pipelining (short live ranges: compiler
        // batches these without spilling — r0: 68 VGPR, WRITE=33MB)
        float xall[CIN];
        #pragma unroll
        for (int c = 0; c < CIN; ++c)
            xall[c] = inb ? xb[(size_t)c * HIN * WIN] : 0.0f;

        // XOR-swizzle of the 16B chunk within this tap's 128B row:
        // un-swizzled all 16 taps hit the same 4-bank group (16-way conflict).
        const int swz = (tap & 7) << 4;
        char* Abase = reinterpret_cast<char*>(S + p*SP) + tap*128;

        #pragma unroll
        for (int g = 0; g < 8; ++g) {
            uint pk[4];
            #pragma unroll
            for (int pr = 0; pr < 4; ++pr) {
                const int c0 = g*8 + pr*2;
                const uint2 wv2 = wrow[c0 >> 2];
                const uint word = (c0 & 2) ? wv2.y : wv2.x;
                const float w0 = __uint_as_float(word << 16);
                const float w1 = __uint_as_float(word & 0xffff0000u);
                __hip_bfloat16 p0 = __float2bfloat16(w0 * xall[c0]);
                __hip_bfloat16 p1 = __float2bfloat16(w1 * xall[c0 + 1]);
                const uint lo = *reinterpret_cast<unsigned short*>(&p0);
                const uint hi = *reinterpret_cast<unsigned short*>(&p1);
                pk[pr] = lo | (hi << 16);
            }
            *reinterpret_cast<uint4*>(Abase + ((g*16) ^ swz)) =
                make_uint4(pk[0], pk[1], pk[2], pk[3]);
        }
    }

    __syncthreads();

    // ================= phase 2: out[o][p] = bc[o] + sum_k Wc[o][k']*A[p][k'] =================
    {
        const int o0 = wv * 32;
        const __hip_bfloat16* wcP0 = WcB + ((size_t)(o0 + lm)) * KTOT + quad*8;
        const __hip_bfloat16* wcP1 = wcP0 + (size_t)16 * KTOT;
        const char* aRow = reinterpret_cast<const char*>(S + lm*SP);
        const int qoff = quad << 4;

        f32x4 acc0 = {0.f,0.f,0.f,0.f};
        f32x4 acc1 = {0.f,0.f,0.f,0.f};

        #pragma unroll 8
        for (int ks = 0; ks < KTOT/32; ++ks) {
            const int tap = ks >> 1;
            const int rem = ((ks & 1) << 6) + qoff;               // byte offset within tap row
            const bf16x8 af = *reinterpret_cast<const bf16x8*>(
                aRow + tap*128 + (rem ^ ((tap & 7) << 4)));       // matches writer swizzle
            const bf16x8 w0 = *reinterpret_cast<const bf16x8*>(wcP0 + ks*32);
            const bf16x8 w1 = *reinterpret_cast<const bf16x8*>(wcP1 + ks*32);
            __builtin_amdgcn_s_setprio(1);
            acc0 = __builtin_amdgcn_mfma_f32_16x16x32_bf16(w0, af, acc0, 0, 0, 0);
            acc1 = __builtin_amdgcn_mfma_f32_16x16x32_bf16(w1, af, acc1, 0, 0, 0);
            __builtin_amdgcn_s_setprio(0);
        }

        #pragma unroll
        for (int q = 0; q < 4; ++q) {
            const int oa = o0 + quad*4 + q;
            const int ob = oa + 16;
            out[(((size_t)b*COUT + oa)*HOUT + ho)*WOUT + wo0 + lm] = acc0[q] + bc[oa];
            out[(((size_t)b*COUT + ob)*HOUT + ho)*WOUT + wo0 + lm] = acc1[q] + bc[ob];
        }
    }
}

} // namespace

extern "C" void kernel_launch(void* const* d_in, const int* in_sizes, int n_in,
                              void* d_out, int out_size, void* d_ws, size_t ws_size,
                              hipStream_t stream) {
    const float* x  = (const float*)d_in[0];
    const float* r  = (const float*)d_in[1];
    const float* W1 = (const float*)d_in[2];
    const float* b1 = (const float*)d_in[3];
    const float* W2 = (const float*)d_in[4];
    const float* b2 = (const float*)d_in[5];
    const float* Wc = (const float*)d_in[6];
    const float* bc = (const float*)d_in[7];
    float* out = (float*)d_out;

    __hip_bfloat16* wcb = (__hip_bfloat16*)d_ws;                       // 256 KB
    __hip_bfloat16* w2t = (__hip_bfloat16*)((char*)d_ws + 262144);     // 8 KB

    const int ntot = COUT*KTOT + CIN*CIN;   // 135168
    hipLaunchKernelGGL(cvt_wts, dim3((ntot + 255)/256), dim3(256), 0, stream,
                       Wc, W2, wcb, w2t);

    dim3 grid(B_ * HOUT * (WOUT / TW));   // 4096
    dim3 block(256);
    hipLaunchKernelGGL(fused_ccconv, grid, block, 0, stream,
                       x, r, W1, b1, w2t, b2, wcb, bc, out);
}

// Round 4
// 292.263 us; speedup vs baseline: 1.1600x; 1.0005x over previous
//
#include <hip/hip_runtime.h>
#include <hip/hip_bf16.h>

namespace {

constexpr int B_   = 4;
constexpr int CIN  = 64;
constexpr int COUT = 128;
constexpr int HIN  = 64,  WIN  = 1024;
constexpr int HOUT = 32,  WOUT = 512;
constexpr int TW   = 16;        // wo positions per block
constexpr int SP   = 1096;      // per-position S stride in bf16 elems (2192 B: mult16, !=0 mod 128)
constexpr int KTOT = CIN * 16;  // 1024

typedef __bf16 bf16x8 __attribute__((ext_vector_type(8)));
typedef float  f32x4  __attribute__((ext_vector_type(4)));

// wcb[o][tap*64+c] = Wc[o][c*16+tap] (bf16);  w2t[c][c1] = W2[c1][c] (bf16)
__global__ void cvt_wts(const float* __restrict__ Wc, const float* __restrict__ W2,
                        __hip_bfloat16* __restrict__ wcb, __hip_bfloat16* __restrict__ w2t) {
    int i = blockIdx.x * 256 + threadIdx.x;
    if (i < COUT * KTOT) {
        int o = i >> 10, k = i & 1023, tap = k >> 6, c = k & 63;
        wcb[i] = __float2bfloat16(Wc[(size_t)o * KTOT + c * 16 + tap]);
    } else if (i < COUT * KTOT + CIN * CIN) {
        int m = i - COUT * KTOT;
        int c = m >> 6, c1 = m & 63;
        w2t[m] = __float2bfloat16(W2[c1 * CIN + c]);
    }
}

// (256,2): ~256-VGPR budget so phase 1c can keep ALL 64 x-loads in flight
// (short live range within 1c — this is NOT the r1/r2 cross-phase hoist,
// which spilled). At (256,3)'s 68-VGPR cap the compiler split xall into
// ~4 batches, re-exposing 300-900cy L2/HBM latency each time. Occupancy
// drops 12->8 waves/CU; r0-r3 show latency exposure, not wave count, binds.
__global__ __launch_bounds__(256, 2)
void fused_ccconv(const float* __restrict__ x,  const float* __restrict__ r,
                  const float* __restrict__ W1, const float* __restrict__ b1,
                  const __hip_bfloat16* __restrict__ W2T, const float* __restrict__ b2,
                  const __hip_bfloat16* __restrict__ WcB, const float* __restrict__ bc,
                  float* __restrict__ out)
{
    // Per position p: elems [0,1088) hold w[tap][c] (stride 68, b64-aligned) during phase 1,
    // then A[k'=tap*64+c] overwrites [0,1024) in phase 1c (same wave owns both -> in-order DS).
    // A's 16B chunks are XOR-swizzled within each 128B tap-row to kill ds_write bank conflicts
    // (proven r1-r3: SQ_LDS_BANK_CONFLICT 9.4M -> 2.1M).
    __shared__ __hip_bfloat16 S[TW * SP];   // 35,072 B

    const int t   = threadIdx.x;
    const int bx  = blockIdx.x;
    const int wt  = bx & 31;
    const int ho  = (bx >> 5) & 31;
    const int b   = bx >> 10;
    const int wo0 = wt * TW;

    const float* rb = r + (size_t)b * HIN * WIN;

    // ---- output 1: r_center ----
    if (t < TW) {
        const int wo = wo0 + t;
        out[(size_t)B_*COUT*HOUT*WOUT + ((size_t)b*HOUT + ho)*WOUT + wo] =
            rb[(2*ho + 1)*WIN + (2*wo + 1)];
    }

    const int ln   = t & 63;
    const int wv   = t >> 6;
    const int lm   = ln & 15;
    const int quad = ln >> 4;

    const float AZI = 0.006135923151542565f;  // 2*pi/1024
    const float INC = 0.0073f;

    // ================= phase 1b: w = leaky(pe@W1+b1)@W2 + b2 via MFMA =================
    {
        // B-frags (W2T) from global, L1-hot: lane holds W2T[nt*16+lm][k..k+7]
        bf16x8 bfr[4][2];
        float  b2v[4];
        #pragma unroll
        for (int nt = 0; nt < 4; ++nt) {
            #pragma unroll
            for (int ks = 0; ks < 2; ++ks)
                bfr[nt][ks] = *reinterpret_cast<const bf16x8*>(
                    W2T + (nt*16 + lm)*CIN + ks*32 + quad*8);
            b2v[nt] = b2[nt*16 + lm];
        }

        // this lane's tap (A-operand row) = lm
        const int i_ = lm >> 2, j_ = lm & 3;
        const float di = (float)(i_ - 2), dj = (float)(j_ - 2);
        const float cA = cosf(AZI * dj), sA = sinf(AZI * dj);
        const float cI = cosf(INC * di), sI = sinf(INC * di);
        const int hsrc = (2*ho + j_ + 63) & 63;

        #pragma unroll
        for (int mt = 0; mt < 4; ++mt) {
            const int p  = wv*4 + mt;
            const int wo = wo0 + p;
            const int wsrc = 2*wo + i_ - 1;
            const bool inb = (unsigned)wsrc < (unsigned)WIN;
            const float rpv = inb ? rb[hsrc*WIN + wsrc] : 100.0f;
            const float rc  = rb[(2*ho + 1)*WIN + (2*wo + 1)];
            const float pe0 = rpv * cA * cI - rc;
            const float pe1 = rpv * cA * sI;
            const float pe2 = rpv * sA;

            // A-frags: lane holds h[tap=lm][c1 = ks*32 + quad*8 + j]
            bf16x8 af0, af1;
            #pragma unroll
            for (int ks = 0; ks < 2; ++ks) {
                const int cb = ks*32 + quad*8;
                #pragma unroll
                for (int j = 0; j < 8; ++j) {
                    const int c1 = cb + j;
                    float hv = fmaf(pe0, W1[c1],
                               fmaf(pe1, W1[CIN + c1],
                               fmaf(pe2, W1[2*CIN + c1], b1[c1])));
                    hv = (hv >= 0.0f) ? hv : 0.2f * hv;
                    __hip_bfloat16 hb = __float2bfloat16(hv);
                    if (ks == 0) af0[j] = *reinterpret_cast<__bf16*>(&hb);
                    else         af1[j] = *reinterpret_cast<__bf16*>(&hb);
                }
            }

            #pragma unroll
            for (int nt = 0; nt < 4; ++nt) {
                f32x4 acc = {b2v[nt], b2v[nt], b2v[nt], b2v[nt]};
                acc = __builtin_amdgcn_mfma_f32_16x16x32_bf16(af0, bfr[nt][0], acc, 0, 0, 0);
                acc = __builtin_amdgcn_mfma_f32_16x16x32_bf16(af1, bfr[nt][1], acc, 0, 0, 0);
                // D: row(tap) = quad*4+q, col(c) = nt*16+lm  -> w[tap][c], stride 68
                #pragma unroll
                for (int q = 0; q < 4; ++q)
                    S[p*SP + (quad*4 + q)*68 + nt*16 + lm] = __float2bfloat16(acc[q]);
            }
        }
    }

    // ================= phase 1c: A[p][tap*64+c] = w[tap][c] * x =================
    {
        const int p   = t >> 4;
        const int tap = t & 15;
        const int i_  = tap >> 2, j_ = tap & 3;
        const int hsrc = (2*ho + j_ + 63) & 63;
        const int wo   = wo0 + p;
        const int wsrc = 2*wo + i_ - 1;
        const bool inb = (unsigned)wsrc < (unsigned)WIN;

        const float* xb = x + (size_t)b*CIN*HIN*WIN + hsrc*WIN + wsrc;

        // Issue ALL x loads first (global, 300-900cy) so the wrow LDS reads
        // below overlap their latency. Short live range -> batches to the
        // VGPR budget without spilling (r0: WRITE=33MB at 68 VGPR).
        float xall[CIN];
        #pragma unroll
        for (int c = 0; c < CIN; ++c)
            xall[c] = inb ? xb[(size_t)c * HIN * WIN] : 0.0f;

        // read this row's w (in-order DS => all reads precede the A-writes below)
        uint2 wrow[16];
        const uint2* wp = reinterpret_cast<const uint2*>(S + p*SP + tap*68);
        #pragma unroll
        for (int u = 0; u < 16; ++u) wrow[u] = wp[u];

        // XOR-swizzle of the 16B chunk within this tap's 128B row:
        // un-swizzled all 16 taps hit the same 4-bank group (16-way conflict).
        const int swz = (tap & 7) << 4;
        char* Abase = reinterpret_cast<char*>(S + p*SP) + tap*128;

        #pragma unroll
        for (int g = 0; g < 8; ++g) {
            uint pk[4];
            #pragma unroll
            for (int pr = 0; pr < 4; ++pr) {
                const int c0 = g*8 + pr*2;
                const uint2 wv2 = wrow[c0 >> 2];
                const uint word = (c0 & 2) ? wv2.y : wv2.x;
                const float w0 = __uint_as_float(word << 16);
                const float w1 = __uint_as_float(word & 0xffff0000u);
                __hip_bfloat16 p0 = __float2bfloat16(w0 * xall[c0]);
                __hip_bfloat16 p1 = __float2bfloat16(w1 * xall[c0 + 1]);
                const uint lo = *reinterpret_cast<unsigned short*>(&p0);
                const uint hi = *reinterpret_cast<unsigned short*>(&p1);
                pk[pr] = lo | (hi << 16);
            }
            *reinterpret_cast<uint4*>(Abase + ((g*16) ^ swz)) =
                make_uint4(pk[0], pk[1], pk[2], pk[3]);
        }
    }

    __syncthreads();

    // ================= phase 2: out[o][p] = bc[o] + sum_k Wc[o][k']*A[p][k'] =================
    {
        const int o0 = wv * 32;
        const __hip_bfloat16* wcP0 = WcB + ((size_t)(o0 + lm)) * KTOT + quad*8;
        const __hip_bfloat16* wcP1 = wcP0 + (size_t)16 * KTOT;
        const char* aRow = reinterpret_cast<const char*>(S + lm*SP);
        const int qoff = quad << 4;

        f32x4 acc0 = {0.f,0.f,0.f,0.f};
        f32x4 acc1 = {0.f,0.f,0.f,0.f};

        #pragma unroll 8
        for (int ks = 0; ks < KTOT/32; ++ks) {
            const int tap = ks >> 1;
            const int rem = ((ks & 1) << 6) + qoff;               // byte offset within tap row
            const bf16x8 af = *reinterpret_cast<const bf16x8*>(
                aRow + tap*128 + (rem ^ ((tap & 7) << 4)));       // matches writer swizzle
            const bf16x8 w0 = *reinterpret_cast<const bf16x8*>(wcP0 + ks*32);
            const bf16x8 w1 = *reinterpret_cast<const bf16x8*>(wcP1 + ks*32);
            acc0 = __builtin_amdgcn_mfma_f32_16x16x32_bf16(w0, af, acc0, 0, 0, 0);
            acc1 = __builtin_amdgcn_mfma_f32_16x16x32_bf16(w1, af, acc1, 0, 0, 0);
        }

        #pragma unroll
        for (int q = 0; q < 4; ++q) {
            const int oa = o0 + quad*4 + q;
            const int ob = oa + 16;
            out[(((size_t)b*COUT + oa)*HOUT + ho)*WOUT + wo0 + lm] = acc0[q] + bc[oa];
            out[(((size_t)b*COUT + ob)*HOUT + ho)*WOUT + wo0 + lm] = acc1[q] + bc[ob];
        }
    }
}

} // namespace

extern "C" void kernel_launch(void* const* d_in, const int* in_sizes, int n_in,
                              void* d_out, int out_size, void* d_ws, size_t ws_size,
                              hipStream_t stream) {
    const float* x  = (const float*)d_in[0];
    const float* r  = (const float*)d_in[1];
    const float* W1 = (const float*)d_in[2];
    const float* b1 = (const float*)d_in[3];
    const float* W2 = (const float*)d_in[4];
    const float* b2 = (const float*)d_in[5];
    const float* Wc = (const float*)d_in[6];
    const float* bc = (const float*)d_in[7];
    float* out = (float*)d_out;

    __hip_bfloat16* wcb = (__hip_bfloat16*)d_ws;                       // 256 KB
    __hip_bfloat16* w2t = (__hip_bfloat16*)((char*)d_ws + 262144);     // 8 KB

    const int ntot = COUT*KTOT + CIN*CIN;   // 135168
    hipLaunchKernelGGL(cvt_wts, dim3((ntot + 255)/256), dim3(256), 0, stream,
                       Wc, W2, wcb, w2t);

    dim3 grid(B_ * HOUT * (WOUT / TW));   // 4096
    dim3 block(256);
    hipLaunchKernelGGL(fused_ccconv, grid, block, 0, stream,
                       x, r, W1, b1, w2t, b2, wcb, bc, out);
}

// Round 6
// 291.443 us; speedup vs baseline: 1.1632x; 1.0028x over previous
//
#include <hip/hip_runtime.h>
#include <hip/hip_bf16.h>

namespace {

constexpr int B_   = 4;
constexpr int CIN  = 64;
constexpr int COUT = 128;
constexpr int HIN  = 64,  WIN  = 1024;
constexpr int HOUT = 32,  WOUT = 512;
constexpr int TW   = 16;        // wo positions per block
constexpr int KTOT = CIN * 16;  // 1024

typedef __bf16 bf16x8 __attribute__((ext_vector_type(8)));
typedef float  f32x4  __attribute__((ext_vector_type(4)));

// wcb[o][tap*64+c] = Wc[o][c*16+tap] (bf16);  w2t[c][c1] = W2[c1][c] (bf16)
__global__ void cvt_wts(const float* __restrict__ Wc, const float* __restrict__ W2,
                        __hip_bfloat16* __restrict__ wcb, __hip_bfloat16* __restrict__ w2t) {
    int i = blockIdx.x * 256 + threadIdx.x;
    if (i < COUT * KTOT) {
        int o = i >> 10, k = i & 1023, tap = k >> 6, c = k & 63;
        wcb[i] = __float2bfloat16(Wc[(size_t)o * KTOT + c * 16 + tap]);
    } else if (i < COUT * KTOT + CIN * CIN) {
        int m = i - COUT * KTOT;
        int c = m >> 6, c1 = m & 63;
        w2t[m] = __float2bfloat16(W2[c1 * CIN + c]);
    }
}

// S is EXACTLY 32 KiB (was 35,328 B): 160 KiB LDS pool / 32 KiB = 5 blocks/CU
// (was 3). r0-r4: all pipes <15% busy, wave lifetime ~96K cy vs ~7K issue ->
// wall = (blocks/CU / concurrency) x lifetime; concurrency is the open lever.
// Padding (SP=1096, stride 68) existed only for bank conflicts, which r3 PROVED
// are off the critical path (-7.3M conflict cycles = 0 time). Replaced with
// XOR swizzles (w-rows at 8B granularity, A-chunks at 16B granularity).
__global__ __launch_bounds__(256, 3)
void fused_ccconv(const float* __restrict__ x,  const float* __restrict__ r,
                  const float* __restrict__ W1, const float* __restrict__ b1,
                  const __hip_bfloat16* __restrict__ W2T, const float* __restrict__ b2,
                  const __hip_bfloat16* __restrict__ WcB, const float* __restrict__ bc,
                  float* __restrict__ out)
{
    // Per position p (2 KiB region): phase 1b writes w[row][col] at
    //   elem = row*64 + (col ^ ((row&7)<<2))           (8B-chunk XOR swizzle)
    // phase 1c overwrites the same region with A[tap][c] at
    //   byte = tap*128 + ((chunk16*16) ^ (((tap^p)&7)<<4))
    // Each w row is read (wrow) ONLY by the same lane that overwrites it with A,
    // and 1b/1c for a position live on the same wave -> in-order DS, no barrier.
    __shared__ __hip_bfloat16 S[TW * 1024];   // 32,768 B exactly

    const int t   = threadIdx.x;
    const int bx  = blockIdx.x;
    const int wt  = bx & 31;
    const int ho  = (bx >> 5) & 31;
    const int b   = bx >> 10;
    const int wo0 = wt * TW;

    const float* rb = r + (size_t)b * HIN * WIN;

    // ---- output 1: r_center ----
    if (t < TW) {
        const int wo = wo0 + t;
        out[(size_t)B_*COUT*HOUT*WOUT + ((size_t)b*HOUT + ho)*WOUT + wo] =
            rb[(2*ho + 1)*WIN + (2*wo + 1)];
    }

    const int ln   = t & 63;
    const int wv   = t >> 6;
    const int lm   = ln & 15;
    const int quad = ln >> 4;

    const float AZI = 0.006135923151542565f;  // 2*pi/1024
    const float INC = 0.0073f;

    // ================= phase 1b: w = leaky(pe@W1+b1)@W2 + b2 via MFMA =================
    {
        // B-frags (W2T) from global, L1-hot: lane holds W2T[nt*16+lm][k..k+7]
        bf16x8 bfr[4][2];
        float  b2v[4];
        #pragma unroll
        for (int nt = 0; nt < 4; ++nt) {
            #pragma unroll
            for (int ks = 0; ks < 2; ++ks)
                bfr[nt][ks] = *reinterpret_cast<const bf16x8*>(
                    W2T + (nt*16 + lm)*CIN + ks*32 + quad*8);
            b2v[nt] = b2[nt*16 + lm];
        }

        // this lane's tap (A-operand row) = lm
        const int i_ = lm >> 2, j_ = lm & 3;
        const float di = (float)(i_ - 2), dj = (float)(j_ - 2);
        const float cA = cosf(AZI * dj), sA = sinf(AZI * dj);
        const float cI = cosf(INC * di), sI = sinf(INC * di);
        const int hsrc = (2*ho + j_ + 63) & 63;

        #pragma unroll
        for (int mt = 0; mt < 4; ++mt) {
            const int p  = wv*4 + mt;
            const int wo = wo0 + p;
            const int wsrc = 2*wo + i_ - 1;
            const bool inb = (unsigned)wsrc < (unsigned)WIN;
            const float rpv = inb ? rb[hsrc*WIN + wsrc] : 100.0f;
            const float rc  = rb[(2*ho + 1)*WIN + (2*wo + 1)];
            const float pe0 = rpv * cA * cI - rc;
            const float pe1 = rpv * cA * sI;
            const float pe2 = rpv * sA;

            // A-frags: lane holds h[tap=lm][c1 = ks*32 + quad*8 + j]
            bf16x8 af0, af1;
            #pragma unroll
            for (int ks = 0; ks < 2; ++ks) {
                const int cb = ks*32 + quad*8;
                #pragma unroll
                for (int j = 0; j < 8; ++j) {
                    const int c1 = cb + j;
                    float hv = fmaf(pe0, W1[c1],
                               fmaf(pe1, W1[CIN + c1],
                               fmaf(pe2, W1[2*CIN + c1], b1[c1])));
                    hv = (hv >= 0.0f) ? hv : 0.2f * hv;
                    __hip_bfloat16 hb = __float2bfloat16(hv);
                    if (ks == 0) af0[j] = *reinterpret_cast<__bf16*>(&hb);
                    else         af1[j] = *reinterpret_cast<__bf16*>(&hb);
                }
            }

            #pragma unroll
            for (int nt = 0; nt < 4; ++nt) {
                f32x4 acc = {b2v[nt], b2v[nt], b2v[nt], b2v[nt]};
                acc = __builtin_amdgcn_mfma_f32_16x16x32_bf16(af0, bfr[nt][0], acc, 0, 0, 0);
                acc = __builtin_amdgcn_mfma_f32_16x16x32_bf16(af1, bfr[nt][1], acc, 0, 0, 0);
                // D: row(tap) = quad*4+q, col(c) = nt*16+lm -> w[row][col],
                // stored with 8B-chunk XOR swizzle within the 128B row
                #pragma unroll
                for (int q = 0; q < 4; ++q) {
                    const int row = quad*4 + q;
                    S[p*1024 + row*64 + ((nt*16 + lm) ^ ((row & 7) << 2))] =
                        __float2bfloat16(acc[q]);
                }
            }
        }
    }

    // ================= phase 1c: A[p][tap*64+c] = w[tap][c] * x =================
    {
        const int p   = t >> 4;
        const int tap = t & 15;
        const int i_  = tap >> 2, j_ = tap & 3;
        const int hsrc = (2*ho + j_ + 63) & 63;
        const int wo   = wo0 + p;
        const int wsrc = 2*wo + i_ - 1;
        const bool inb = (unsigned)wsrc < (unsigned)WIN;

        const float* xb = x + (size_t)b*CIN*HIN*WIN + hsrc*WIN + wsrc;

        // prefetch all x (short live ranges; r0-r4: no spill at 68 VGPR)
        float xall[CIN];
        #pragma unroll
        for (int c = 0; c < CIN; ++c)
            xall[c] = inb ? xb[(size_t)c * HIN * WIN] : 0.0f;

        // read this row's w: logical 8B chunk u sits at physical chunk u^(tap&7)
        const int ws = tap & 7;
        uint2 wrow[16];
        const uint2* wp = reinterpret_cast<const uint2*>(S + p*1024 + tap*64);
        #pragma unroll
        for (int u = 0; u < 16; ++u) wrow[u] = wp[u ^ ws];

        // A-writes: 16B chunk g -> physical chunk g ^ ((tap^p)&7)
        const int swz = ((tap ^ p) & 7) << 4;
        char* Abase = reinterpret_cast<char*>(S + p*1024) + tap*128;

        #pragma unroll
        for (int g = 0; g < 8; ++g) {
            uint pk[4];
            #pragma unroll
            for (int pr = 0; pr < 4; ++pr) {
                const int c0 = g*8 + pr*2;
                const uint2 wv2 = wrow[c0 >> 2];
                const uint word = (c0 & 2) ? wv2.y : wv2.x;
                const float w0 = __uint_as_float(word << 16);
                const float w1 = __uint_as_float(word & 0xffff0000u);
                __hip_bfloat16 p0 = __float2bfloat16(w0 * xall[c0]);
                __hip_bfloat16 p1 = __float2bfloat16(w1 * xall[c0 + 1]);
                const uint lo = *reinterpret_cast<unsigned short*>(&p0);
                const uint hi = *reinterpret_cast<unsigned short*>(&p1);
                pk[pr] = lo | (hi << 16);
            }
            *reinterpret_cast<uint4*>(Abase + ((g*16) ^ swz)) =
                make_uint4(pk[0], pk[1], pk[2], pk[3]);
        }
    }

    __syncthreads();

    // ================= phase 2: out[o][p] = bc[o] + sum_k Wc[o][k']*A[p][k'] =================
    {
        const int o0 = wv * 32;
        const __hip_bfloat16* wcP0 = WcB + ((size_t)(o0 + lm)) * KTOT + quad*8;
        const __hip_bfloat16* wcP1 = wcP0 + (size_t)16 * KTOT;
        const char* aRow = reinterpret_cast<const char*>(S) + lm*2048;
        const int qoff = quad << 4;

        f32x4 acc0 = {0.f,0.f,0.f,0.f};
        f32x4 acc1 = {0.f,0.f,0.f,0.f};

        #pragma unroll 8
        for (int ks = 0; ks < KTOT/32; ++ks) {
            const int tap = ks >> 1;
            const int rem = ((ks & 1) << 6) + qoff;   // logical byte offset in tap row
            const bf16x8 af = *reinterpret_cast<const bf16x8*>(
                aRow + tap*128 + (rem ^ (((tap ^ lm) & 7) << 4)));  // matches writer
            const bf16x8 w0 = *reinterpret_cast<const bf16x8*>(wcP0 + ks*32);
            const bf16x8 w1 = *reinterpret_cast<const bf16x8*>(wcP1 + ks*32);
            acc0 = __builtin_amdgcn_mfma_f32_16x16x32_bf16(w0, af, acc0, 0, 0, 0);
            acc1 = __builtin_amdgcn_mfma_f32_16x16x32_bf16(w1, af, acc1, 0, 0, 0);
        }

        #pragma unroll
        for (int q = 0; q < 4; ++q) {
            const int oa = o0 + quad*4 + q;
            const int ob = oa + 16;
            out[(((size_t)b*COUT + oa)*HOUT + ho)*WOUT + wo0 + lm] = acc0[q] + bc[oa];
            out[(((size_t)b*COUT + ob)*HOUT + ho)*WOUT + wo0 + lm] = acc1[q] + bc[ob];
        }
    }
}

} // namespace

extern "C" void kernel_launch(void* const* d_in, const int* in_sizes, int n_in,
                              void* d_out, int out_size, void* d_ws, size_t ws_size,
                              hipStream_t stream) {
    const float* x  = (const float*)d_in[0];
    const float* r  = (const float*)d_in[1];
    const float* W1 = (const float*)d_in[2];
    const float* b1 = (const float*)d_in[3];
    const float* W2 = (const float*)d_in[4];
    const float* b2 = (const float*)d_in[5];
    const float* Wc = (const float*)d_in[6];
    const float* bc = (const float*)d_in[7];
    float* out = (float*)d_out;

    __hip_bfloat16* wcb = (__hip_bfloat16*)d_ws;                       // 256 KB
    __hip_bfloat16* w2t = (__hip_bfloat16*)((char*)d_ws + 262144);     // 8 KB

    const int ntot = COUT*KTOT + CIN*CIN;   // 135168
    hipLaunchKernelGGL(cvt_wts, dim3((ntot + 255)/256), dim3(256), 0, stream,
                       Wc, W2, wcb, w2t);

    dim3 grid(B_ * HOUT * (WOUT / TW));   // 4096
    dim3 block(256);
    hipLaunchKernelGGL(fused_ccconv, grid, block, 0, stream,
                       x, r, W1, b1, w2t, b2, wcb, bc, out);
}